// Round 14
// baseline (74.308 us; speedup 1.0000x reference)
//
#include <hip/hip_runtime.h>
#include <hip/hip_fp16.h>

#define D_  160
#define H_  192
#define W_  224
#define HW_ (H_ * W_)           // 43008
#define HW2_ (HW_ / 2)          // 21504
#define N_  (D_ * H_ * W_)      // 6881280
#define INV729 (1.0f / 729.0f)
#define HSEG 12
#define NSEG (H_ / HSEG)        // 16 strips
#define NROW (HSEG + 9)         // 21 rows pushed per strip

// Intermediate: bufA = uint4 per 2 points (c0..c3 pt0, c0..c3 pt1, fp16)
//               bufB = dword per 2 points (c4 pt0, c4 pt1, fp16)

__device__ __forceinline__ unsigned pack2(float a, float b) {
    const __half2 h = __floats2half2_rn(a, b);
    return *(const unsigned*)&h;
}

// ---------------------------------------------------------------------------
// Fused W+H box-sum — full-row waves, 4 pts/lane, conflict-free b128 LDS.
// Wave = (d, h-strip). Lanes 0..57 stage 4-float chunks (w=4c-4..4c-1) of
// both arrays; lanes 0..55 compute 4 outputs from a 12-float window read as
// 3 contiguous ds_read_b128 per array. fp16-packed H-ring (exact-cancel).
__global__ __launch_bounds__(256, 3) void k_passWH(const float* __restrict__ pred,
                                                   const float* __restrict__ targ,
                                                   uint4* __restrict__ outA,      // [N/2]
                                                   unsigned* __restrict__ outB,   // [N/2]
                                                   double* __restrict__ acc) {
    __shared__ __attribute__((aligned(16))) float lds[4][2][2][240]; // [wave][buf][arr][f]
    if (blockIdx.x == 0 && threadIdx.x == 0) *acc = 0.0;  // stream-ordered before k_passD

    const int wid  = threadIdx.x >> 6;
    const int lane = threadIdx.x & 63;
    const int unit = blockIdx.x * 4 + wid;
    const int d     = unit / NSEG;
    const int strip = unit % NSEG;
    const int h0    = strip * HSEG;
    const long dbase = (long)d * HW_;

    // staging: lane c<58 owns chunk w = 4c-4 .. 4c-1 (region floats 4c..4c+3)
    const int  ws  = 4 * lane - 4;
    const bool cok = (lane < 58) && (ws >= 0) && (ws + 3 < W_);
    const int  wsc = ws < 0 ? 0 : (ws > W_ - 4 ? W_ - 4 : ws);
    const float* gI = targ + dbase + wsc;   // Ii = target
    const float* gJ = pred + dbase + wsc;   // Ji = pred

    // fp16 H-ring: q[c][ph] = {half2(pt0,pt1), half2(pt2,pt3)}
    uint2 q[5][9];
    #pragma unroll
    for (int c = 0; c < 5; ++c)
        #pragma unroll
        for (int k = 0; k < 9; ++k) q[c][k] = make_uint2(0u, 0u);
    float S[5][4];
    #pragma unroll
    for (int c = 0; c < 5; ++c)
        #pragma unroll
        for (int j = 0; j < 4; ++j) S[c][j] = 0.f;

    auto fI = [&](int r) -> float4 {
        const int hh = h0 - 5 + r;
        const int hc = hh < 0 ? 0 : (hh >= H_ ? H_ - 1 : hh);
        float4 f = *(const float4*)(gI + (long)hc * W_);
        if (!(cok && hh >= 0 && hh < H_)) f = make_float4(0.f, 0.f, 0.f, 0.f);
        return f;
    };
    auto fJ = [&](int r) -> float4 {
        const int hh = h0 - 5 + r;
        const int hc = hh < 0 ? 0 : (hh >= H_ ? H_ - 1 : hh);
        float4 f = *(const float4*)(gJ + (long)hc * W_);
        if (!(cok && hh >= 0 && hh < H_)) f = make_float4(0.f, 0.f, 0.f, 0.f);
        return f;
    };

    // 2-deep prefetch: slot s holds row r, r&1 == s
    float4 pI[2], pJ[2];
    pI[0] = fI(0); pJ[0] = fJ(0);
    pI[1] = fI(1); pJ[1] = fJ(1);
    if (lane < 58) {            // prologue: write row 0 into buf 0
        *(float4*)&lds[wid][0][0][4 * lane] = pI[0];
        *(float4*)&lds[wid][0][1][4 * lane] = pJ[0];
    }
    pI[0] = fI(2); pJ[0] = fJ(2);

    #pragma unroll
    for (int p = 0; p < NROW; ++p) {
        const int sl = (p + 1) & 1;          // slot/buffer for row p+1
        const int cb = p & 1;                // buffer holding row p
        if (lane < 58) {                     // write row p+1 (fetched 2 steps ago)
            *(float4*)&lds[wid][sl][0][4 * lane] = pI[sl];
            *(float4*)&lds[wid][sl][1][4 * lane] = pJ[sl];
        }
        pI[sl] = fI(p + 3); pJ[sl] = fJ(p + 3);   // refill (rows >NROW-1 zeroed)

        if (lane < 56) {                     // compute row p: pts w = 4l..4l+3
            const float* bI = &lds[wid][cb][0][0];
            const float* bJ = &lds[wid][cb][1][0];
            float x[12], y[12];
            #pragma unroll
            for (int m = 0; m < 3; ++m) {    // contiguous 16B/lane -> no conflicts
                const float4 vx = *(const float4*)&bI[4 * lane + 4 * m];
                const float4 vy = *(const float4*)&bJ[4 * lane + 4 * m];
                x[4*m] = vx.x; x[4*m+1] = vx.y; x[4*m+2] = vx.z; x[4*m+3] = vx.w;
                y[4*m] = vy.x; y[4*m+1] = vy.y; y[4*m+2] = vy.z; y[4*m+3] = vy.w;
            }
            // window sums for 4 points: 9-wide base + 3 incremental slides
            float wI[4], wJ[4], wII[4], wJJ[4], wIJ[4];
            float aI = 0.f, aJ = 0.f, aII = 0.f, aJJ = 0.f, aIJ = 0.f;
            #pragma unroll
            for (int k = 0; k < 9; ++k) {
                aI += x[k]; aJ += y[k];
                aII = fmaf(x[k], x[k], aII);
                aJJ = fmaf(y[k], y[k], aJJ);
                aIJ = fmaf(x[k], y[k], aIJ);
            }
            wI[0] = aI; wJ[0] = aJ; wII[0] = aII; wJJ[0] = aJJ; wIJ[0] = aIJ;
            #pragma unroll
            for (int j = 1; j < 4; ++j) {
                aI  += x[8+j] - x[j-1];
                aJ  += y[8+j] - y[j-1];
                aII += x[8+j]*x[8+j] - x[j-1]*x[j-1];
                aJJ += y[8+j]*y[8+j] - y[j-1]*y[j-1];
                aIJ += x[8+j]*y[8+j] - x[j-1]*y[j-1];
                wI[j] = aI; wJ[j] = aJ; wII[j] = aII; wJJ[j] = aJJ; wIJ[j] = aIJ;
            }

            const int ph = p % 9;            // compile-time (full unroll)
            // fp16 ring update: S += unpack(pack(w)) - old  (exact cancel)
            #define RINGUP(c, W0, W1, W2, W3)                                   \
            {   const unsigned n01 = pack2(W0, W1), n23 = pack2(W2, W3);        \
                const float2 f01 = __half22float2(*(const __half2*)&n01);       \
                const float2 f23 = __half22float2(*(const __half2*)&n23);       \
                const float2 o01 = __half22float2(*(const __half2*)&q[c][ph].x);\
                const float2 o23 = __half22float2(*(const __half2*)&q[c][ph].y);\
                S[c][0] += f01.x - o01.x;  S[c][1] += f01.y - o01.y;            \
                S[c][2] += f23.x - o23.x;  S[c][3] += f23.y - o23.y;            \
                q[c][ph] = make_uint2(n01, n23); }
            RINGUP(0, wI[0],  wI[1],  wI[2],  wI[3])
            RINGUP(1, wJ[0],  wJ[1],  wJ[2],  wJ[3])
            RINGUP(2, wII[0], wII[1], wII[2], wII[3])
            RINGUP(3, wJJ[0], wJJ[1], wJJ[2], wJJ[3])
            RINGUP(4, wIJ[0], wIJ[1], wIJ[2], wIJ[3])
            #undef RINGUP

            if (p >= 9) {                    // emit row h0+p-9
                const long rb2 = (dbase + (long)(h0 + p - 9) * W_) / 2;
                uint4 o0, o1;
                o0.x = pack2(S[0][0], S[1][0]); o0.y = pack2(S[2][0], S[3][0]);
                o0.z = pack2(S[0][1], S[1][1]); o0.w = pack2(S[2][1], S[3][1]);
                o1.x = pack2(S[0][2], S[1][2]); o1.y = pack2(S[2][2], S[3][2]);
                o1.z = pack2(S[0][3], S[1][3]); o1.w = pack2(S[2][3], S[3][3]);
                outA[rb2 + 2 * lane]     = o0;
                outA[rb2 + 2 * lane + 1] = o1;
                *(uint2*)&outB[rb2 + 2 * lane] =
                    make_uint2(pack2(S[4][0], S[4][1]), pack2(S[4][2], S[4][3]));
            }
        }
    }
}

// ---------------------------------------------------------------------------
// D-axis 9-tap sliding sum + cc + reduction. TWO points per thread: one b128
// (bufA) + one b32 (bufB) per d-step. (unchanged — proven ~10 us)
__global__ __launch_bounds__(256) void k_passD(const uint4* __restrict__ bufA,
                                               const unsigned* __restrict__ bufB,
                                               double* __restrict__ acc) {
    const int DSEG = D_ / 8;                // 20
    const int p2 = blockIdx.x * blockDim.x + threadIdx.x;   // < HW2_
    const int d0 = blockIdx.y * DSEG;

    float2 q[5][9], S[5];                   // .x = pt0, .y = pt1
    #pragma unroll
    for (int c = 0; c < 5; ++c) S[c] = make_float2(0.f, 0.f);

    #pragma unroll
    for (int k = 0; k < 9; ++k) {
        const int dd = d0 - 5 + k;          // d0+3 <= 143 < 160
        uint4 va = make_uint4(0u, 0u, 0u, 0u);
        unsigned vb = 0u;
        if (dd >= 0) {
            va = bufA[(long)dd * HW2_ + p2];
            vb = bufB[(long)dd * HW2_ + p2];
        }
        const float2 a01 = __half22float2(*(const __half2*)&va.x);
        const float2 a23 = __half22float2(*(const __half2*)&va.y);
        const float2 b01 = __half22float2(*(const __half2*)&va.z);
        const float2 b23 = __half22float2(*(const __half2*)&va.w);
        const float2 c44 = __half22float2(*(const __half2*)&vb);
        q[0][k] = make_float2(a01.x, b01.x); S[0].x += a01.x; S[0].y += b01.x;
        q[1][k] = make_float2(a01.y, b01.y); S[1].x += a01.y; S[1].y += b01.y;
        q[2][k] = make_float2(a23.x, b23.x); S[2].x += a23.x; S[2].y += b23.x;
        q[3][k] = make_float2(a23.y, b23.y); S[3].x += a23.y; S[3].y += b23.y;
        q[4][k] = make_float2(c44.x, c44.y); S[4].x += c44.x; S[4].y += c44.y;
    }

    float myacc = 0.f;
    #pragma unroll
    for (int j = 0; j < DSEG; ++j) {        // output d = d0+j
        const int dd = d0 + 4 + j;
        uint4 va = make_uint4(0u, 0u, 0u, 0u);
        unsigned vb = 0u;
        if (dd < D_) {
            va = bufA[(long)dd * HW2_ + p2];
            vb = bufB[(long)dd * HW2_ + p2];
        }
        const float2 a01 = __half22float2(*(const __half2*)&va.x);
        const float2 a23 = __half22float2(*(const __half2*)&va.y);
        const float2 b01 = __half22float2(*(const __half2*)&va.z);
        const float2 b23 = __half22float2(*(const __half2*)&va.w);
        const float2 c44 = __half22float2(*(const __half2*)&vb);
        const float2 nv[5] = {
            make_float2(a01.x, b01.x), make_float2(a01.y, b01.y),
            make_float2(a23.x, b23.x), make_float2(a23.y, b23.y),
            make_float2(c44.x, c44.y)
        };
        const int ph = j % 9;               // compile-time
        #pragma unroll
        for (int c = 0; c < 5; ++c) {
            S[c].x += nv[c].x - q[c][ph].x;
            S[c].y += nv[c].y - q[c][ph].y;
            q[c][ph] = nv[c];
        }
        #pragma unroll
        for (int e = 0; e < 2; ++e) {
            const float mu1 = (e ? S[0].y : S[0].x) * INV729;
            const float mu2 = (e ? S[1].y : S[1].x) * INV729;
            const float s1  = (e ? S[2].y : S[2].x) * INV729 - mu1 * mu1;
            const float s2  = (e ? S[3].y : S[3].x) * INV729 - mu2 * mu2;
            const float s12 = (e ? S[4].y : S[4].x) * INV729 - mu1 * mu2;
            const float den = fmaxf(s1 * s2, 1.1920929e-7f);  // finfo(f32).eps
            myacc += (s12 * s12) / den;
        }
    }

    __shared__ float red[256];
    red[threadIdx.x] = myacc;
    __syncthreads();
    #pragma unroll
    for (int s = 128; s > 0; s >>= 1) {
        if (threadIdx.x < s) red[threadIdx.x] += red[threadIdx.x + s];
        __syncthreads();
    }
    if (threadIdx.x == 0) atomicAdd(acc, (double)red[0]);
}

// ---------------------------------------------------------------------------
__global__ void k_fin(const double* __restrict__ acc, float* __restrict__ out) {
    out[0] = (float)(-(*acc) / (double)N_);
}

// ---------------------------------------------------------------------------
extern "C" void kernel_launch(void* const* d_in, const int* in_sizes, int n_in,
                              void* d_out, int out_size, void* d_ws, size_t ws_size,
                              hipStream_t stream) {
    const float* pred = (const float*)d_in[0];
    const float* targ = (const float*)d_in[1];

    uint4*    bufA = (uint4*)d_ws;                                 // N/2 x 16B
    unsigned* bufB = (unsigned*)((char*)d_ws + (size_t)(N_ / 2) * 16);  // N/2 x 4B
    double*   acc  = (double*)((char*)d_ws + (size_t)(N_ / 2) * 16 + (size_t)(N_ / 2) * 4);
    float*    out  = (float*)d_out;

    // 2560 full-row wave-units (160 d x 16 strips), 4 waves/block -> 640 blocks
    k_passWH<<<D_ * NSEG / 4, 256, 0, stream>>>(pred, targ, bufA, bufB, acc);
    dim3 g3(HW2_ / 256, 8);     // 84 x 8 = 672 blocks
    k_passD<<<g3, 256, 0, stream>>>(bufA, bufB, acc);
    k_fin<<<1, 1, 0, stream>>>(acc, out);
}

// Round 15
// 73.207 us; speedup vs baseline: 1.0150x; 1.0150x over previous
//
#include <hip/hip_runtime.h>
#include <hip/hip_fp16.h>

#define D_  160
#define H_  192
#define W_  224
#define HW_ (H_ * W_)           // 43008
#define HW2_ (HW_ / 2)          // 21504
#define N_  (D_ * H_ * W_)      // 6881280
#define INV729 (1.0f / 729.0f)
#define HSEG 12
#define NSEG (H_ / HSEG)        // 16 strips
#define NROW (HSEG + 9)         // 21 rows pushed per strip

// Intermediate (pair-PERMUTED layout; D-pass is order-agnostic in the HW
// plane as long as WH and D use the same p2 index for the same point):
//   bufA[row*112 + lane]      = c0..c3 of pts (4*lane, 4*lane+1)   lane<56
//   bufA[row*112 + 56 + lane] = c0..c3 of pts (4*lane+2, 4*lane+3)
//   bufB same permutation, 1 dword per pair.

__device__ __forceinline__ unsigned pack2(float a, float b) {
    const __half2 h = __floats2half2_rn(a, b);
    return *(const unsigned*)&h;
}

// ---------------------------------------------------------------------------
// Fused W+H box-sum — full-row waves, 4 pts/lane, conflict-free b128 LDS,
// CONTIGUOUS per-instruction global stores (fixes R14's 2x write amp).
__global__ __launch_bounds__(256, 3) void k_passWH(const float* __restrict__ pred,
                                                   const float* __restrict__ targ,
                                                   uint4* __restrict__ outA,      // [N/2]
                                                   unsigned* __restrict__ outB,   // [N/2]
                                                   double* __restrict__ acc) {
    __shared__ __attribute__((aligned(16))) float lds[4][2][2][240]; // [wave][buf][arr][f]
    if (blockIdx.x == 0 && threadIdx.x == 0) *acc = 0.0;  // stream-ordered before k_passD

    const int wid  = threadIdx.x >> 6;
    const int lane = threadIdx.x & 63;
    const int unit = blockIdx.x * 4 + wid;
    const int d     = unit / NSEG;
    const int strip = unit % NSEG;
    const int h0    = strip * HSEG;
    const long dbase = (long)d * HW_;

    // staging: lane c<58 owns chunk w = 4c-4 .. 4c-1 (region floats 4c..4c+3)
    const int  ws  = 4 * lane - 4;
    const bool cok = (lane < 58) && (ws >= 0) && (ws + 3 < W_);
    const int  wsc = ws < 0 ? 0 : (ws > W_ - 4 ? W_ - 4 : ws);
    const float* gI = targ + dbase + wsc;   // Ii = target
    const float* gJ = pred + dbase + wsc;   // Ji = pred

    // fp16 H-ring: q[c][ph] = {half2(pt0,pt1), half2(pt2,pt3)}
    uint2 q[5][9];
    #pragma unroll
    for (int c = 0; c < 5; ++c)
        #pragma unroll
        for (int k = 0; k < 9; ++k) q[c][k] = make_uint2(0u, 0u);
    float S[5][4];
    #pragma unroll
    for (int c = 0; c < 5; ++c)
        #pragma unroll
        for (int j = 0; j < 4; ++j) S[c][j] = 0.f;

    auto fI = [&](int r) -> float4 {
        if (r >= NROW) return make_float4(0.f, 0.f, 0.f, 0.f);  // compile-time pruned
        const int hh = h0 - 5 + r;
        const int hc = hh < 0 ? 0 : (hh >= H_ ? H_ - 1 : hh);
        float4 f = *(const float4*)(gI + (long)hc * W_);
        if (!(cok && hh >= 0 && hh < H_)) f = make_float4(0.f, 0.f, 0.f, 0.f);
        return f;
    };
    auto fJ = [&](int r) -> float4 {
        if (r >= NROW) return make_float4(0.f, 0.f, 0.f, 0.f);
        const int hh = h0 - 5 + r;
        const int hc = hh < 0 ? 0 : (hh >= H_ ? H_ - 1 : hh);
        float4 f = *(const float4*)(gJ + (long)hc * W_);
        if (!(cok && hh >= 0 && hh < H_)) f = make_float4(0.f, 0.f, 0.f, 0.f);
        return f;
    };

    // 2-deep prefetch: slot s holds row r, r&1 == s
    float4 pI[2], pJ[2];
    pI[0] = fI(0); pJ[0] = fJ(0);
    pI[1] = fI(1); pJ[1] = fJ(1);
    if (lane < 58) {            // prologue: write row 0 into buf 0
        *(float4*)&lds[wid][0][0][4 * lane] = pI[0];
        *(float4*)&lds[wid][0][1][4 * lane] = pJ[0];
    }
    pI[0] = fI(2); pJ[0] = fJ(2);

    #pragma unroll
    for (int p = 0; p < NROW; ++p) {
        const int sl = (p + 1) & 1;          // slot/buffer for row p+1
        const int cb = p & 1;                // buffer holding row p
        if (lane < 58) {                     // write row p+1 (fetched 2 steps ago)
            *(float4*)&lds[wid][sl][0][4 * lane] = pI[sl];
            *(float4*)&lds[wid][sl][1][4 * lane] = pJ[sl];
        }
        pI[sl] = fI(p + 3); pJ[sl] = fJ(p + 3);   // refill

        if (lane < 56) {                     // compute row p: pts w = 4l..4l+3
            const float* bI = &lds[wid][cb][0][0];
            const float* bJ = &lds[wid][cb][1][0];
            float x[12], y[12];
            #pragma unroll
            for (int m = 0; m < 3; ++m) {    // contiguous 16B/lane -> no conflicts
                const float4 vx = *(const float4*)&bI[4 * lane + 4 * m];
                const float4 vy = *(const float4*)&bJ[4 * lane + 4 * m];
                x[4*m] = vx.x; x[4*m+1] = vx.y; x[4*m+2] = vx.z; x[4*m+3] = vx.w;
                y[4*m] = vy.x; y[4*m+1] = vy.y; y[4*m+2] = vy.z; y[4*m+3] = vy.w;
            }
            // window sums for 4 points: 9-wide base + 3 incremental slides
            float wI[4], wJ[4], wII[4], wJJ[4], wIJ[4];
            float aI = 0.f, aJ = 0.f, aII = 0.f, aJJ = 0.f, aIJ = 0.f;
            #pragma unroll
            for (int k = 0; k < 9; ++k) {
                aI += x[k]; aJ += y[k];
                aII = fmaf(x[k], x[k], aII);
                aJJ = fmaf(y[k], y[k], aJJ);
                aIJ = fmaf(x[k], y[k], aIJ);
            }
            wI[0] = aI; wJ[0] = aJ; wII[0] = aII; wJJ[0] = aJJ; wIJ[0] = aIJ;
            #pragma unroll
            for (int j = 1; j < 4; ++j) {
                aI  += x[8+j] - x[j-1];
                aJ  += y[8+j] - y[j-1];
                aII += x[8+j]*x[8+j] - x[j-1]*x[j-1];
                aJJ += y[8+j]*y[8+j] - y[j-1]*y[j-1];
                aIJ += x[8+j]*y[8+j] - x[j-1]*y[j-1];
                wI[j] = aI; wJ[j] = aJ; wII[j] = aII; wJJ[j] = aJJ; wIJ[j] = aIJ;
            }

            const int ph = p % 9;            // compile-time (full unroll)
            // fp16 ring update: S += unpack(pack(w)) - old  (exact cancel)
            #define RINGUP(c, W0, W1, W2, W3)                                   \
            {   const unsigned n01 = pack2(W0, W1), n23 = pack2(W2, W3);        \
                const float2 f01 = __half22float2(*(const __half2*)&n01);       \
                const float2 f23 = __half22float2(*(const __half2*)&n23);       \
                const float2 o01 = __half22float2(*(const __half2*)&q[c][ph].x);\
                const float2 o23 = __half22float2(*(const __half2*)&q[c][ph].y);\
                S[c][0] += f01.x - o01.x;  S[c][1] += f01.y - o01.y;            \
                S[c][2] += f23.x - o23.x;  S[c][3] += f23.y - o23.y;            \
                q[c][ph] = make_uint2(n01, n23); }
            RINGUP(0, wI[0],  wI[1],  wI[2],  wI[3])
            RINGUP(1, wJ[0],  wJ[1],  wJ[2],  wJ[3])
            RINGUP(2, wII[0], wII[1], wII[2], wII[3])
            RINGUP(3, wJJ[0], wJJ[1], wJJ[2], wJJ[3])
            RINGUP(4, wIJ[0], wIJ[1], wIJ[2], wIJ[3])
            #undef RINGUP

            if (p >= 9) {                    // emit row h0+p-9, PERMUTED pairs:
                const long rb2 = (dbase + (long)(h0 + p - 9) * W_) / 2;
                uint4 o0, o1;                // each store = 16B/lane CONTIGUOUS
                o0.x = pack2(S[0][0], S[1][0]); o0.y = pack2(S[2][0], S[3][0]);
                o0.z = pack2(S[0][1], S[1][1]); o0.w = pack2(S[2][1], S[3][1]);
                o1.x = pack2(S[0][2], S[1][2]); o1.y = pack2(S[2][2], S[3][2]);
                o1.z = pack2(S[0][3], S[1][3]); o1.w = pack2(S[2][3], S[3][3]);
                outA[rb2 + lane]      = o0;  // pair-slot lane      (pts 4l,4l+1)
                outA[rb2 + 56 + lane] = o1;  // pair-slot 56+lane   (pts 4l+2,4l+3)
                outB[rb2 + lane]      = pack2(S[4][0], S[4][1]);
                outB[rb2 + 56 + lane] = pack2(S[4][2], S[4][3]);
            }
        }
    }
}

// ---------------------------------------------------------------------------
// D-axis 9-tap sliding sum + cc + reduction. TWO points per thread: one b128
// (bufA) + one b32 (bufB) per d-step. p2 is the permuted pair index — the
// permutation is d-invariant, so the d-axis ring is unaffected. (proven)
__global__ __launch_bounds__(256) void k_passD(const uint4* __restrict__ bufA,
                                               const unsigned* __restrict__ bufB,
                                               double* __restrict__ acc) {
    const int DSEG = D_ / 8;                // 20
    const int p2 = blockIdx.x * blockDim.x + threadIdx.x;   // < HW2_
    const int d0 = blockIdx.y * DSEG;

    float2 q[5][9], S[5];                   // .x = pt0, .y = pt1
    #pragma unroll
    for (int c = 0; c < 5; ++c) S[c] = make_float2(0.f, 0.f);

    #pragma unroll
    for (int k = 0; k < 9; ++k) {
        const int dd = d0 - 5 + k;          // d0+3 <= 143 < 160
        uint4 va = make_uint4(0u, 0u, 0u, 0u);
        unsigned vb = 0u;
        if (dd >= 0) {
            va = bufA[(long)dd * HW2_ + p2];
            vb = bufB[(long)dd * HW2_ + p2];
        }
        const float2 a01 = __half22float2(*(const __half2*)&va.x);
        const float2 a23 = __half22float2(*(const __half2*)&va.y);
        const float2 b01 = __half22float2(*(const __half2*)&va.z);
        const float2 b23 = __half22float2(*(const __half2*)&va.w);
        const float2 c44 = __half22float2(*(const __half2*)&vb);
        q[0][k] = make_float2(a01.x, b01.x); S[0].x += a01.x; S[0].y += b01.x;
        q[1][k] = make_float2(a01.y, b01.y); S[1].x += a01.y; S[1].y += b01.y;
        q[2][k] = make_float2(a23.x, b23.x); S[2].x += a23.x; S[2].y += b23.x;
        q[3][k] = make_float2(a23.y, b23.y); S[3].x += a23.y; S[3].y += b23.y;
        q[4][k] = make_float2(c44.x, c44.y); S[4].x += c44.x; S[4].y += c44.y;
    }

    float myacc = 0.f;
    #pragma unroll
    for (int j = 0; j < DSEG; ++j) {        // output d = d0+j
        const int dd = d0 + 4 + j;
        uint4 va = make_uint4(0u, 0u, 0u, 0u);
        unsigned vb = 0u;
        if (dd < D_) {
            va = bufA[(long)dd * HW2_ + p2];
            vb = bufB[(long)dd * HW2_ + p2];
        }
        const float2 a01 = __half22float2(*(const __half2*)&va.x);
        const float2 a23 = __half22float2(*(const __half2*)&va.y);
        const float2 b01 = __half22float2(*(const __half2*)&va.z);
        const float2 b23 = __half22float2(*(const __half2*)&va.w);
        const float2 c44 = __half22float2(*(const __half2*)&vb);
        const float2 nv[5] = {
            make_float2(a01.x, b01.x), make_float2(a01.y, b01.y),
            make_float2(a23.x, b23.x), make_float2(a23.y, b23.y),
            make_float2(c44.x, c44.y)
        };
        const int ph = j % 9;               // compile-time
        #pragma unroll
        for (int c = 0; c < 5; ++c) {
            S[c].x += nv[c].x - q[c][ph].x;
            S[c].y += nv[c].y - q[c][ph].y;
            q[c][ph] = nv[c];
        }
        #pragma unroll
        for (int e = 0; e < 2; ++e) {
            const float mu1 = (e ? S[0].y : S[0].x) * INV729;
            const float mu2 = (e ? S[1].y : S[1].x) * INV729;
            const float s1  = (e ? S[2].y : S[2].x) * INV729 - mu1 * mu1;
            const float s2  = (e ? S[3].y : S[3].x) * INV729 - mu2 * mu2;
            const float s12 = (e ? S[4].y : S[4].x) * INV729 - mu1 * mu2;
            const float den = fmaxf(s1 * s2, 1.1920929e-7f);  // finfo(f32).eps
            myacc += (s12 * s12) / den;
        }
    }

    __shared__ float red[256];
    red[threadIdx.x] = myacc;
    __syncthreads();
    #pragma unroll
    for (int s = 128; s > 0; s >>= 1) {
        if (threadIdx.x < s) red[threadIdx.x] += red[threadIdx.x + s];
        __syncthreads();
    }
    if (threadIdx.x == 0) atomicAdd(acc, (double)red[0]);
}

// ---------------------------------------------------------------------------
__global__ void k_fin(const double* __restrict__ acc, float* __restrict__ out) {
    out[0] = (float)(-(*acc) / (double)N_);
}

// ---------------------------------------------------------------------------
extern "C" void kernel_launch(void* const* d_in, const int* in_sizes, int n_in,
                              void* d_out, int out_size, void* d_ws, size_t ws_size,
                              hipStream_t stream) {
    const float* pred = (const float*)d_in[0];
    const float* targ = (const float*)d_in[1];

    uint4*    bufA = (uint4*)d_ws;                                 // N/2 x 16B
    unsigned* bufB = (unsigned*)((char*)d_ws + (size_t)(N_ / 2) * 16);  // N/2 x 4B
    double*   acc  = (double*)((char*)d_ws + (size_t)(N_ / 2) * 16 + (size_t)(N_ / 2) * 4);
    float*    out  = (float*)d_out;

    // 2560 full-row wave-units (160 d x 16 strips), 4 waves/block -> 640 blocks
    k_passWH<<<D_ * NSEG / 4, 256, 0, stream>>>(pred, targ, bufA, bufB, acc);
    dim3 g3(HW2_ / 256, 8);     // 84 x 8 = 672 blocks
    k_passD<<<g3, 256, 0, stream>>>(bufA, bufB, acc);
    k_fin<<<1, 1, 0, stream>>>(acc, out);
}

// Round 16
// 58.366 us; speedup vs baseline: 1.2731x; 1.2543x over previous
//
#include <hip/hip_runtime.h>
#include <hip/hip_fp16.h>

#define D_  160
#define H_  192
#define W_  224
#define HW_ (H_ * W_)           // 43008
#define HW2_ (HW_ / 2)          // 21504
#define N_  (D_ * H_ * W_)      // 6881280
#define INV729 (1.0f / 729.0f)
#define HSEG 16
#define NSEG (H_ / HSEG)        // 12
#define NROW (HSEG + 9)         // 25 rows pushed per strip
#define UPD  (NSEG * 2)         // wave-units per d = 24 (2 halves x 12 strips)

// Intermediate: bufA = uint4 per 2 points (c0..c3 pt0, c0..c3 pt1, fp16)
//               bufB = dword per 2 points (c4 pt0, c4 pt1, fp16)

__device__ __forceinline__ unsigned pack2(float a, float b) {
    const __half2 h = __floats2half2_rn(a, b);
    return *(const unsigned*)&h;
}

// ---------------------------------------------------------------------------
// Fused W+H box-sum — one wave per block (64 thr), wave-private LDS with
// I/J-INTERLEAVED float2 entries: window read = 5 x 16B-aligned ds_read_b128
// (R14-proven low-conflict pattern), vs R12's 10 x b64. 3-deep paired
// prefetch with static slots. Ring / stores byte-identical to R12.
__global__ __launch_bounds__(64) void k_passWH(const float* __restrict__ pred,
                                               const float* __restrict__ targ,
                                               uint4* __restrict__ outA,      // [N/2]
                                               unsigned* __restrict__ outB,   // [N/2]
                                               double* __restrict__ acc) {
    __shared__ __attribute__((aligned(16))) float2 lds[2][128];  // [buf][entry]
    if (blockIdx.x == 0 && threadIdx.x == 0) *acc = 0.0;  // before k_passD (stream order)

    const int lane = threadIdx.x;            // one wave per block
    const int unit = blockIdx.x;
    const int d    = unit / UPD;
    const int rem  = unit % UPD;
    const int half = rem & 1;
    const int h0   = (rem >> 1) * HSEG;
    const long dbase = (long)d * HW_;
    const int wbase = half * 112;            // first output w of this half

    // staging: lanes 0..29, chunk j=lane covers w = wbase-4+4j .. +3
    const bool isld = (lane < 30);
    const int  w0c  = wbase - 4 + 4 * lane;
    const bool cok  = isld && (w0c >= 0) && (w0c + 3 < W_);
    const int  wsc  = w0c < 0 ? 0 : (w0c > W_ - 4 ? W_ - 4 : w0c);
    const float* gI = targ + dbase + wsc;    // Ii = target
    const float* gJ = pred + dbase + wsc;    // Ji = pred

    // fp32 H-ring (R12-exact): q[c][ph] = (w-sum pt0, pt1)
    float2 q[5][9];
    #pragma unroll
    for (int c = 0; c < 5; ++c)
        #pragma unroll
        for (int k = 0; k < 9; ++k) q[c][k] = make_float2(0.f, 0.f);
    float S0[5] = {0,0,0,0,0}, S1[5] = {0,0,0,0,0};

    float4 pI[3], pJ[3];                     // 3-deep paired prefetch
    auto fetch = [&](int r, float4& fi, float4& fj) {
        if (r >= NROW) { fi = make_float4(0.f,0.f,0.f,0.f); fj = fi; return; }
        const int hh = h0 - 5 + r;
        const int hc = hh < 0 ? 0 : (hh >= H_ ? H_ - 1 : hh);
        float4 a = *(const float4*)(gI + (long)hc * W_);
        float4 b = *(const float4*)(gJ + (long)hc * W_);
        if (!(cok && hh >= 0 && hh < H_)) {
            a = make_float4(0.f, 0.f, 0.f, 0.f); b = a;
        }
        fi = a; fj = b;
    };
    auto wr = [&](int row, int slot) {       // write 4 interleaved entries
        float2* dst = &lds[row & 1][4 * lane];
        *(float4*)(dst)     = make_float4(pI[slot].x, pJ[slot].x, pI[slot].y, pJ[slot].y);
        *(float4*)(dst + 2) = make_float4(pI[slot].z, pJ[slot].z, pI[slot].w, pJ[slot].w);
    };

    if (isld) {                              // prologue: rows 0,1,2 in flight
        fetch(0, pI[0], pJ[0]);
        fetch(1, pI[1], pJ[1]);
        fetch(2, pI[2], pJ[2]);
        wr(0, 0);                            // row 0 -> buf 0
        fetch(3, pI[0], pJ[0]);              // refill slot 0
    }

    #pragma unroll
    for (int p = 0; p < NROW; ++p) {
        if (isld) {                          // write row p+1, keep 3 in flight
            wr(p + 1, (p + 1) % 3);
            fetch(p + 4, pI[(p + 1) % 3], pJ[(p + 1) % 3]);
        }
        // hazard: reads of buf[p&1] (below) precede the next write to that
        // buffer (row p+2, step p+1) in this wave's program order. DS is
        // FIFO per wave; compiler inserts lgkmcnt. No barriers needed.

        if (lane < 56) {                     // compute row p: pts wbase+2l, +2l+1
            float x[10], y[10];
            #pragma unroll
            for (int m = 0; m < 5; ++m) {    // 16B-aligned b128: {I,J,I,J}
                const float4 v = *(const float4*)&lds[p & 1][2 * lane + 2 * m];
                x[2*m] = v.x; y[2*m] = v.y; x[2*m+1] = v.z; y[2*m+1] = v.w;
            }
            float sI = 0.f, sJ = 0.f, sII = 0.f, sJJ = 0.f, sIJ = 0.f;
            #pragma unroll
            for (int kk = 0; kk < 9; ++kk) {
                sI  += x[kk];          sJ  += y[kk];
                sII = fmaf(x[kk], x[kk], sII);
                sJJ = fmaf(y[kk], y[kk], sJJ);
                sIJ = fmaf(x[kk], y[kk], sIJ);
            }
            float w0[5], w1[5];
            w0[0] = sI;  w1[0] = sI  + x[9] - x[0];
            w0[1] = sJ;  w1[1] = sJ  + y[9] - y[0];
            w0[2] = sII; w1[2] = sII + x[9]*x[9] - x[0]*x[0];
            w0[3] = sJJ; w1[3] = sJJ + y[9]*y[9] - y[0]*y[0];
            w0[4] = sIJ; w1[4] = sIJ + x[9]*y[9] - x[0]*y[0];

            const int ph = p % 9;            // compile-time (full unroll)
            #pragma unroll
            for (int c = 0; c < 5; ++c) {
                S0[c] += w0[c] - q[c][ph].x;
                S1[c] += w1[c] - q[c][ph].y;
                q[c][ph].x = w0[c];
                q[c][ph].y = w1[c];
            }
            if (p >= 9) {                    // emit row h0+p-9 (R12-exact)
                const long rb = dbase + (long)(h0 + p - 9) * W_;  // even
                uint4 oA;
                oA.x = pack2(S0[0], S0[1]); oA.y = pack2(S0[2], S0[3]);
                oA.z = pack2(S1[0], S1[1]); oA.w = pack2(S1[2], S1[3]);
                outA[rb / 2 + half * 56 + lane] = oA;
                outB[rb / 2 + half * 56 + lane] = pack2(S0[4], S1[4]);
            }
        }
    }
}

// ---------------------------------------------------------------------------
// D-axis 9-tap sliding sum + cc + reduction. TWO points per thread: one b128
// (bufA) + one b32 (bufB) per d-step. (unchanged — proven ~10 us)
__global__ __launch_bounds__(256) void k_passD(const uint4* __restrict__ bufA,
                                               const unsigned* __restrict__ bufB,
                                               double* __restrict__ acc) {
    const int DSEG = D_ / 8;                // 20
    const int p2 = blockIdx.x * blockDim.x + threadIdx.x;   // < HW2_
    const int d0 = blockIdx.y * DSEG;

    float2 q[5][9], S[5];                   // .x = pt0, .y = pt1
    #pragma unroll
    for (int c = 0; c < 5; ++c) S[c] = make_float2(0.f, 0.f);

    #pragma unroll
    for (int k = 0; k < 9; ++k) {
        const int dd = d0 - 5 + k;          // d0+3 <= 143 < 160
        uint4 va = make_uint4(0u, 0u, 0u, 0u);
        unsigned vb = 0u;
        if (dd >= 0) {
            va = bufA[(long)dd * HW2_ + p2];
            vb = bufB[(long)dd * HW2_ + p2];
        }
        const float2 a01 = __half22float2(*(const __half2*)&va.x);
        const float2 a23 = __half22float2(*(const __half2*)&va.y);
        const float2 b01 = __half22float2(*(const __half2*)&va.z);
        const float2 b23 = __half22float2(*(const __half2*)&va.w);
        const float2 c44 = __half22float2(*(const __half2*)&vb);
        q[0][k] = make_float2(a01.x, b01.x); S[0].x += a01.x; S[0].y += b01.x;
        q[1][k] = make_float2(a01.y, b01.y); S[1].x += a01.y; S[1].y += b01.y;
        q[2][k] = make_float2(a23.x, b23.x); S[2].x += a23.x; S[2].y += b23.x;
        q[3][k] = make_float2(a23.y, b23.y); S[3].x += a23.y; S[3].y += b23.y;
        q[4][k] = make_float2(c44.x, c44.y); S[4].x += c44.x; S[4].y += c44.y;
    }

    float myacc = 0.f;
    #pragma unroll
    for (int j = 0; j < DSEG; ++j) {        // output d = d0+j
        const int dd = d0 + 4 + j;
        uint4 va = make_uint4(0u, 0u, 0u, 0u);
        unsigned vb = 0u;
        if (dd < D_) {
            va = bufA[(long)dd * HW2_ + p2];
            vb = bufB[(long)dd * HW2_ + p2];
        }
        const float2 a01 = __half22float2(*(const __half2*)&va.x);
        const float2 a23 = __half22float2(*(const __half2*)&va.y);
        const float2 b01 = __half22float2(*(const __half2*)&va.z);
        const float2 b23 = __half22float2(*(const __half2*)&va.w);
        const float2 c44 = __half22float2(*(const __half2*)&vb);
        const float2 nv[5] = {
            make_float2(a01.x, b01.x), make_float2(a01.y, b01.y),
            make_float2(a23.x, b23.x), make_float2(a23.y, b23.y),
            make_float2(c44.x, c44.y)
        };
        const int ph = j % 9;               // compile-time
        #pragma unroll
        for (int c = 0; c < 5; ++c) {
            S[c].x += nv[c].x - q[c][ph].x;
            S[c].y += nv[c].y - q[c][ph].y;
            q[c][ph] = nv[c];
        }
        #pragma unroll
        for (int e = 0; e < 2; ++e) {
            const float mu1 = (e ? S[0].y : S[0].x) * INV729;
            const float mu2 = (e ? S[1].y : S[1].x) * INV729;
            const float s1  = (e ? S[2].y : S[2].x) * INV729 - mu1 * mu1;
            const float s2  = (e ? S[3].y : S[3].x) * INV729 - mu2 * mu2;
            const float s12 = (e ? S[4].y : S[4].x) * INV729 - mu1 * mu2;
            const float den = fmaxf(s1 * s2, 1.1920929e-7f);  // finfo(f32).eps
            myacc += (s12 * s12) / den;
        }
    }

    __shared__ float red[256];
    red[threadIdx.x] = myacc;
    __syncthreads();
    #pragma unroll
    for (int s = 128; s > 0; s >>= 1) {
        if (threadIdx.x < s) red[threadIdx.x] += red[threadIdx.x + s];
        __syncthreads();
    }
    if (threadIdx.x == 0) atomicAdd(acc, (double)red[0]);
}

// ---------------------------------------------------------------------------
__global__ void k_fin(const double* __restrict__ acc, float* __restrict__ out) {
    out[0] = (float)(-(*acc) / (double)N_);
}

// ---------------------------------------------------------------------------
extern "C" void kernel_launch(void* const* d_in, const int* in_sizes, int n_in,
                              void* d_out, int out_size, void* d_ws, size_t ws_size,
                              hipStream_t stream) {
    const float* pred = (const float*)d_in[0];
    const float* targ = (const float*)d_in[1];

    uint4*    bufA = (uint4*)d_ws;                                 // N/2 x 16B
    unsigned* bufB = (unsigned*)((char*)d_ws + (size_t)(N_ / 2) * 16);  // N/2 x 4B
    double*   acc  = (double*)((char*)d_ws + (size_t)(N_ / 2) * 16 + (size_t)(N_ / 2) * 4);
    float*    out  = (float*)d_out;

    // 3840 wave-units (160 d x 12 strips x 2 halves), 1 wave/block
    k_passWH<<<D_ * UPD, 64, 0, stream>>>(pred, targ, bufA, bufB, acc);
    dim3 g3(HW2_ / 256, 8);     // 84 x 8 = 672 blocks
    k_passD<<<g3, 256, 0, stream>>>(bufA, bufB, acc);
    k_fin<<<1, 1, 0, stream>>>(acc, out);
}